// Round 12
// baseline (459.219 us; speedup 1.0000x reference)
//
#include <hip/hip_runtime.h>

#define NHEAD 8
#define NT 256
#define KT 16
#define NTILE 64
#define RS 166          // dwords per m-row in kv tile (8 heads x 20 + 6 pad)
#define HS 20           // per-head stride in dwords
#define OFF_H 1048576
#define OFF_A 34603008

typedef __fp16 h2 __attribute__((ext_vector_type(2)));
typedef __fp16 h8 __attribute__((ext_vector_type(8)));

__device__ __forceinline__ float dot2f(h2 a, h2 b, float c){
#if __has_builtin(__builtin_amdgcn_fdot2)
  return __builtin_amdgcn_fdot2(a, b, c, false);
#else
  return fmaf((float)a[0], (float)b[0], fmaf((float)a[1], (float)b[1], c));
#endif
}

// 256 threads stage a KT=16-row tile: thread covers 16 consecutive floats of one row.
__device__ __forceinline__ void stage_issue(const float* __restrict__ QKV, size_t qkvbase,
                                            int tile, int off, int srow, int scol,
                                            float4 sf[4]){
  const float* src = QKV + qkvbase + (size_t)(tile*KT + srow)*768 + off + scol*16;
  #pragma unroll
  for (int i = 0; i < 4; i++) sf[i] = *(const float4*)(src + i*4);
}

__device__ __forceinline__ void stage_write(h2* kvb, int slot, int srow, int scol,
                                            const float4 sf[4]){
  const float* f = (const float*)sf;   // f[j], j=0..15: c = scol*16+j = d*8+hq
  #pragma unroll
  for (int hq = 0; hq < 8; hq++){
    h2 pk = __builtin_amdgcn_cvt_pkrtz(f[hq], f[8+hq]);   // {K[d0,hq], K[d0+1,hq]}, d0=2*scol
    kvb[(slot*KT + srow)*RS + hq*HS + scol] = pk;
  }
}

__global__ __launch_bounds__(NT, 4) void egt_fused(
    const float* __restrict__ QKV, const float* __restrict__ E,
    const float* __restrict__ G, float* __restrict__ out)
{
  __shared__ __align__(16) h2 kvb[2*KT*RS];   // K/V ring, 2 slots (21.2 KB)
  __shared__ __align__(16) h2 at2h[2][KT][9]; // A fragments fp16 {l0,l1}, dbuf (1.2 KB)
  __shared__ float red[4][NHEAD];
  __shared__ float fin[2][NHEAD];

  const int t   = threadIdx.x;
  const int h   = t & 7;
  const int mg  = (t >> 3) & 15;   // m within tile (mapping-1)
  const int lh  = t >> 7;          // which of the 2 l-rows
  const int w   = t >> 6;
  const int srow = t >> 4;         // staging decode: row 0..15
  const int scol = t & 15;         // 16-float chunk within row
  const int dp  = (t >> 3) & 15;   // PV decode: d-pair 0..15
  const int z   = t >> 7;          // PV m-half
  const int b  = blockIdx.x >> 9;
  const int l0 = (blockIdx.x & 511) << 1;
  const size_t qkvbase = (size_t)(b * 1024) * 768;

  const int ebase = (b*1024 + l0 + lh) * 8192;
  const int eoff  = mg*8 + h;      // == t&127

  // ---- pack Q (one l-row per thread) ----
  h2 q[16];
  {
    const float* qp = QKV + qkvbase + (size_t)(l0 + lh) * 768 + h;
    #pragma unroll
    for (int jd = 0; jd < 16; jd++)
      q[jd] = __builtin_amdgcn_cvt_pkrtz(qp[jd*16], qp[jd*16 + 8]);
  }

  float4 sf[2][4];
  float  e2[2];

  // ---- phase-1 prologue: K(0),K(1) + E(0),E(1) in flight ----
  stage_issue(QKV, qkvbase, 0, 256, srow, scol, sf[0]);
  stage_issue(QKV, qkvbase, 1, 256, srow, scol, sf[1]);
  e2[0] = E[ebase + eoff];
  e2[1] = E[ebase + 128 + eoff];
  stage_write(kvb, 0, srow, scol, sf[0]);
  __syncthreads();

  float sm = 0.f;

  // ---- phase 1: H_hat = clip(QK^T)+E; no-max expsum ----
  #pragma unroll 2
  for (int k = 0; k < NTILE; k++){
    const float e0 = e2[k&1];
    if (k+2 < NTILE){
      stage_issue(QKV, qkvbase, k+2, 256, srow, scol, sf[k&1]);
      e2[k&1] = E[ebase + (k+2)*128 + eoff];
    }
    if (k+1 < NTILE) stage_write(kvb, (k+1)&1, srow, scol, sf[(k+1)&1]);

    float acc = 0.f;
    const h2* kr = &kvb[((k&1)*KT + mg)*RS + h*HS];
    #pragma unroll
    for (int jw = 0; jw < 4; jw++){
      h8 kk = *(const h8*)&kr[jw*4];
      #pragma unroll
      for (int u = 0; u < 4; u++){
        h2 kj; kj[0] = kk[2*u]; kj[1] = kk[2*u+1];
        acc = dot2f(q[jw*4+u], kj, acc);
      }
    }
    float h0 = fminf(fmaxf(acc, -5.f), 5.f) + e0;
    out[OFF_H + ebase + k*128 + eoff] = h0;
    sm += __expf(h0);
    __syncthreads();
  }

  // ---- phase-2 V prefetch overlaps the sum reduction ----
  stage_issue(QKV, qkvbase, 0, 512, srow, scol, sf[0]);
  stage_issue(QKV, qkvbase, 1, 512, srow, scol, sf[1]);

  // ---- expsum reduce over mg (bits 3..5 in-wave, bit 6 across waves) ----
  sm += __shfl_xor(sm, 8); sm += __shfl_xor(sm, 16); sm += __shfl_xor(sm, 32);
  if ((t & 63) < 8) red[w][h] = sm;
  __syncthreads();
  const float rcp = 1.f / (red[2*lh][h] + red[2*lh+1][h]);

  // ---- phase-2 prologue: A(0) computed; G/H(1),(2) in flight ----
  float gh[2][2];
  float dg;
  {
    float ga = G[ebase + eoff];
    float ha = out[OFF_H + ebase + eoff];
    gh[1][0] = G[ebase + 128 + eoff];
    gh[1][1] = out[OFF_H + ebase + 128 + eoff];
    gh[0][0] = G[ebase + 256 + eoff];
    gh[0][1] = out[OFF_H + ebase + 256 + eoff];
    float sig = 1.f / (1.f + __expf(-ga));
    float A0 = __expf(ha) * rcp * sig;
    dg = sig;
    out[OFF_A + ebase + eoff] = A0;
    ((__fp16*)&at2h[0][mg][h])[lh] = (__fp16)A0;
    stage_write(kvb, 0, srow, scol, sf[0]);
  }
  __syncthreads();

  float vacc[2][2] = {{0.f,0.f},{0.f,0.f}};

  // ---- phase 2: A(k+1) pipelined ahead of PV(k); 1 barrier/tile ----
  #pragma unroll 2
  for (int k = 0; k < NTILE; k++){
    if (k+2 < NTILE) stage_issue(QKV, qkvbase, k+2, 512, srow, scol, sf[k&1]);

    if (k+1 < NTILE){
      const int a = k+1;
      float ga = gh[a&1][0], ha = gh[a&1][1];
      if (a+2 < NTILE){
        gh[a&1][0] = G[ebase + (a+2)*128 + eoff];
        gh[a&1][1] = out[OFF_H + ebase + (a+2)*128 + eoff];
      }
      float sig = 1.f / (1.f + __expf(-ga));
      float A0 = __expf(ha) * rcp * sig;
      dg += sig;
      out[OFF_A + ebase + a*128 + eoff] = A0;
      ((__fp16*)&at2h[a&1][mg][h])[lh] = (__fp16)A0;
      stage_write(kvb, a&1, srow, scol, sf[a&1]);
    }

    // PV: thread (h, dp, z) over its 8 m-rows
    #pragma unroll
    for (int j = 0; j < 8; j++){
      const int mm = z*8 + j;
      h2 vv = kvb[((k&1)*KT + mm)*RS + h*HS + dp];
      h2 aa = at2h[k&1][mm][h];
      float v0 = (float)vv[0], v1 = (float)vv[1];
      float a0 = (float)aa[0], a1 = (float)aa[1];
      vacc[0][0] = fmaf(a0, v0, vacc[0][0]);
      vacc[0][1] = fmaf(a0, v1, vacc[0][1]);
      vacc[1][0] = fmaf(a1, v0, vacc[1][0]);
      vacc[1][1] = fmaf(a1, v1, vacc[1][1]);
    }
    __syncthreads();
  }

  // ---- degrees -> log1p scalers ----
  dg += __shfl_xor(dg, 8); dg += __shfl_xor(dg, 16); dg += __shfl_xor(dg, 32);
  if ((t & 63) < 8) red[w][h] = dg;
  __syncthreads();
  if (t < 16){
    int tl = t >> 3, th = t & 7;
    fin[tl][th] = log1pf(red[2*tl][th] + red[2*tl+1][th]);
  }
  __syncthreads();

  // ---- cross-z reduce of PV partials (reuse kvb as float scratch) ----
  float* zb = (float*)kvb;
  if (z == 1)
    *(float4*)&zb[(t & 127) * 4] = make_float4(vacc[0][0], vacc[0][1], vacc[1][0], vacc[1][1]);
  __syncthreads();
  if (z == 0){
    float4 o = *(const float4*)&zb[(t & 127) * 4];
    float r00 = vacc[0][0] + o.x, r01 = vacc[0][1] + o.y;
    float r10 = vacc[1][0] + o.z, r11 = vacc[1][1] + o.w;
    float s0 = fin[0][h], s1 = fin[1][h];
    const int obase = (b*1024 + l0) * 256;
    out[obase +       (2*dp+0)*8 + h] = r00 * s0;
    out[obase +       (2*dp+1)*8 + h] = r01 * s0;
    out[obase + 256 + (2*dp+0)*8 + h] = r10 * s1;
    out[obase + 256 + (2*dp+1)*8 + h] = r11 * s1;
  }
}

extern "C" void kernel_launch(void* const* d_in, const int* in_sizes, int n_in,
                              void* d_out, int out_size, void* d_ws, size_t ws_size,
                              hipStream_t stream) {
  const float* QKV = (const float*)d_in[0];
  const float* E   = (const float*)d_in[1];
  const float* G   = (const float*)d_in[2];
  float* out = (float*)d_out;
  dim3 grid(2048);
  egt_fused<<<grid, NT, 0, stream>>>(QKV, E, G, out);
}